// Round 1
// baseline (8604.787 us; speedup 1.0000x reference)
//
#include <hip/hip_runtime.h>

// Problem constants
#define BB 64       // batch
#define TT 512      // time steps
#define II 128      // input dim
#define HH 512      // hidden
#define CC 5        // out classes

// ---------------------------------------------------------------------------
// GEMM: out[m][n] = sum_k A[m][k] * W[n][k] + b1[n] + b2[n]
// M = 32768 (grid.x=256 * BM=128), N = 512 (grid.y=4 * BN=128), K in {128,512}
// ---------------------------------------------------------------------------
__global__ __launch_bounds__(256) void gemm_bias_kernel(
    const float* __restrict__ A, const float* __restrict__ W,
    const float* __restrict__ b1, const float* __restrict__ b2,
    float* __restrict__ out, int K)
{
    __shared__ float As[16][132];   // +4 pad: 16B-aligned rows, 2-way max on stores
    __shared__ float Bs[16][132];
    const int tid = threadIdx.x;
    const int bm = blockIdx.x;      // 0..255
    const int bn = blockIdx.y;      // 0..3
    const int tx = tid & 15;        // n micro-tile
    const int ty = tid >> 4;        // m micro-tile
    const int lr = tid >> 2;        // load row 0..63
    const int lk = (tid & 3) << 2;  // load k quad

    const float* Ab = A + (size_t)bm * 128 * K;
    const float* Wb = W + (size_t)bn * 128 * K;

    float acc[8][8];
#pragma unroll
    for (int i = 0; i < 8; ++i)
#pragma unroll
        for (int j = 0; j < 8; ++j) acc[i][j] = 0.f;

    for (int k0 = 0; k0 < K; k0 += 16) {
        float4 a0 = *(const float4*)(Ab + (size_t)lr * K + k0 + lk);
        float4 a1 = *(const float4*)(Ab + (size_t)(lr + 64) * K + k0 + lk);
        float4 w0 = *(const float4*)(Wb + (size_t)lr * K + k0 + lk);
        float4 w1 = *(const float4*)(Wb + (size_t)(lr + 64) * K + k0 + lk);
        __syncthreads();   // protect previous iteration's LDS reads
        As[lk + 0][lr] = a0.x; As[lk + 1][lr] = a0.y; As[lk + 2][lr] = a0.z; As[lk + 3][lr] = a0.w;
        As[lk + 0][lr + 64] = a1.x; As[lk + 1][lr + 64] = a1.y; As[lk + 2][lr + 64] = a1.z; As[lk + 3][lr + 64] = a1.w;
        Bs[lk + 0][lr] = w0.x; Bs[lk + 1][lr] = w0.y; Bs[lk + 2][lr] = w0.z; Bs[lk + 3][lr] = w0.w;
        Bs[lk + 0][lr + 64] = w1.x; Bs[lk + 1][lr + 64] = w1.y; Bs[lk + 2][lr + 64] = w1.z; Bs[lk + 3][lr + 64] = w1.w;
        __syncthreads();
#pragma unroll
        for (int k = 0; k < 16; ++k) {
            float4 av0 = *(const float4*)&As[k][ty * 8];
            float4 av1 = *(const float4*)&As[k][ty * 8 + 4];
            float4 bv0 = *(const float4*)&Bs[k][tx * 8];
            float4 bv1 = *(const float4*)&Bs[k][tx * 8 + 4];
            float a[8] = {av0.x, av0.y, av0.z, av0.w, av1.x, av1.y, av1.z, av1.w};
            float b[8] = {bv0.x, bv0.y, bv0.z, bv0.w, bv1.x, bv1.y, bv1.z, bv1.w};
#pragma unroll
            for (int i = 0; i < 8; ++i)
#pragma unroll
                for (int j = 0; j < 8; ++j)
                    acc[i][j] = fmaf(a[i], b[j], acc[i][j]);
        }
    }

    const int nb = bn * 128 + tx * 8;
    float bias[8];
#pragma unroll
    for (int j = 0; j < 8; ++j) bias[j] = b1[nb + j] + b2[nb + j];
#pragma unroll
    for (int i = 0; i < 8; ++i) {
        const size_t m = (size_t)bm * 128 + ty * 8 + i;
        float4 o0 = {acc[i][0] + bias[0], acc[i][1] + bias[1], acc[i][2] + bias[2], acc[i][3] + bias[3]};
        float4 o1 = {acc[i][4] + bias[4], acc[i][5] + bias[5], acc[i][6] + bias[6], acc[i][7] + bias[7]};
        *(float4*)(out + m * HH + nb) = o0;
        *(float4*)(out + m * HH + nb + 4) = o1;
    }
}

// ---------------------------------------------------------------------------
// Recurrent scan for one layer.
// Grid: 256 blocks of 512 threads. blockIdx = s*32 + g:
//   s = row-slice 0..7 (64 rows of W_hh), g = group 0..31 (batches 2g, 2g+1).
// The 8 blocks of a group share b%8 -> same-XCD heuristic for sync latency.
// W slice lives in VGPRs (64 floats/thread, fully unrolled). h exchanged
// via device-scope atomics + release/acquire flags, double-buffered by t&1.
// ---------------------------------------------------------------------------
__global__ __launch_bounds__(512) void scan_kernel(
    const float* __restrict__ xp, const float* __restrict__ Whh,
    float* __restrict__ y, float* hbuf, int* flags)
{
    __shared__ float h_cur[2 * HH];      // [2][512]
    __shared__ float part[8][2][64];     // [k-wave][batch][row]

    const int tid  = threadIdx.x;
    const int s    = blockIdx.x >> 5;    // slice 0..7
    const int g    = blockIdx.x & 31;    // group 0..31
    const int lane = tid & 63;
    const int wv   = tid >> 6;           // wave 0..7 -> k-range [64*wv, 64*wv+64)
    const int row  = s * 64 + lane;      // output row this lane owns

    // --- load W slice into registers (resident for all 512 steps) ---
    float wreg[64];
    {
        const float* wr = Whh + (size_t)row * HH + wv * 64;
#pragma unroll
        for (int i = 0; i < 16; ++i) {
            float4 v = *(const float4*)(wr + 4 * i);
            wreg[4 * i] = v.x; wreg[4 * i + 1] = v.y; wreg[4 * i + 2] = v.z; wreg[4 * i + 3] = v.w;
        }
    }

    h_cur[tid] = 0.f;
    h_cur[tid + 512] = 0.f;

    // reducer-thread coordinates (tid < 128): rb = local batch, rj = local row
    const int rb = tid >> 6;
    const int rj = tid & 63;
    const int gb = g * 2 + rb;           // global batch
    float xp_cur = 0.f;
    if (tid < 128) xp_cur = xp[((size_t)gb * TT + 0) * HH + s * 64 + rj];
    __syncthreads();

    for (int t = 0; t < TT; ++t) {
        if (t > 0) {
            // wait for all 8 slices of step t-1 to be published
            if (tid < 8) {
                while (__hip_atomic_load(&flags[g * 8 + tid], __ATOMIC_ACQUIRE,
                                         __HIP_MEMORY_SCOPE_AGENT) < t) { }
            }
            __syncthreads();
            float* src = hbuf + ((size_t)(t & 1) * 32 + g) * 1024;
            float v0 = __hip_atomic_load(src + tid,       __ATOMIC_RELAXED, __HIP_MEMORY_SCOPE_AGENT);
            float v1 = __hip_atomic_load(src + tid + 512, __ATOMIC_RELAXED, __HIP_MEMORY_SCOPE_AGENT);
            h_cur[tid] = v0;
            h_cur[tid + 512] = v1;
            __syncthreads();
        }

        // --- partial dot products: this wave's 64-wide k-slice, both batches ---
        float acc0 = 0.f, acc1 = 0.f;
        const int kb = wv * 64;
#pragma unroll
        for (int i = 0; i < 16; ++i) {
            float4 h0 = *(const float4*)&h_cur[kb + 4 * i];          // broadcast
            float4 h1 = *(const float4*)&h_cur[512 + kb + 4 * i];    // broadcast
            acc0 = fmaf(wreg[4 * i],     h0.x, acc0);
            acc0 = fmaf(wreg[4 * i + 1], h0.y, acc0);
            acc0 = fmaf(wreg[4 * i + 2], h0.z, acc0);
            acc0 = fmaf(wreg[4 * i + 3], h0.w, acc0);
            acc1 = fmaf(wreg[4 * i],     h1.x, acc1);
            acc1 = fmaf(wreg[4 * i + 1], h1.y, acc1);
            acc1 = fmaf(wreg[4 * i + 2], h1.z, acc1);
            acc1 = fmaf(wreg[4 * i + 3], h1.w, acc1);
        }
        part[wv][0][lane] = acc0;
        part[wv][1][lane] = acc1;
        __syncthreads();

        if (tid < 128) {
            float sum = part[0][rb][rj];
#pragma unroll
            for (int w = 1; w < 8; ++w) sum += part[w][rb][rj];
            float hn = fmaxf(sum + xp_cur, 0.f);
            // layer output y[b][t][h]
            y[((size_t)gb * TT + t) * HH + s * 64 + rj] = hn;
            // publish h_{t+1} slice
            float* dst = hbuf + ((size_t)((t + 1) & 1) * 32 + g) * 1024 + rb * 512 + s * 64 + rj;
            __hip_atomic_store(dst, hn, __ATOMIC_RELAXED, __HIP_MEMORY_SCOPE_AGENT);
            // prefetch next xp (latency hidden behind next step)
            if (t < TT - 1) xp_cur = xp[((size_t)gb * TT + (t + 1)) * HH + s * 64 + rj];
        }
        __syncthreads();   // drains vmcnt: hbuf stores visible before flag
        if (tid == 0) {
            __hip_atomic_store(&flags[g * 8 + s], t + 1, __ATOMIC_RELEASE,
                               __HIP_MEMORY_SCOPE_AGENT);
        }
    }
}

// ---------------------------------------------------------------------------
// Head: out[b][c] = sum_h y[b][T-1][h] * W_out[c][h] + b_out[c]
// One wave per (b,c).
// ---------------------------------------------------------------------------
__global__ __launch_bounds__(64) void head_kernel(
    const float* __restrict__ y2, const float* __restrict__ Wout,
    const float* __restrict__ bout, float* __restrict__ out)
{
    const int bc = blockIdx.x;        // 0..319
    const int b = bc / CC, c = bc % CC;
    const int lane = threadIdx.x;
    const float* yrow = y2 + ((size_t)b * TT + (TT - 1)) * HH;
    const float* wrow = Wout + (size_t)c * HH;
    float s = 0.f;
#pragma unroll
    for (int i = 0; i < HH / 64; ++i)
        s = fmaf(yrow[lane + 64 * i], wrow[lane + 64 * i], s);
#pragma unroll
    for (int off = 32; off > 0; off >>= 1) s += __shfl_down(s, off);
    if (lane == 0) out[bc] = s + bout[c];
}

// ---------------------------------------------------------------------------
extern "C" void kernel_launch(void* const* d_in, const int* in_sizes, int n_in,
                              void* d_out, int out_size, void* d_ws, size_t ws_size,
                              hipStream_t stream)
{
    const float* x = (const float*)d_in[0];
    const float* W_ih[3] = {(const float*)d_in[1], (const float*)d_in[5], (const float*)d_in[9]};
    const float* W_hh[3] = {(const float*)d_in[2], (const float*)d_in[6], (const float*)d_in[10]};
    const float* b_ih[3] = {(const float*)d_in[3], (const float*)d_in[7], (const float*)d_in[11]};
    const float* b_hh[3] = {(const float*)d_in[4], (const float*)d_in[8], (const float*)d_in[12]};
    const float* W_out = (const float*)d_in[13];
    const float* b_out = (const float*)d_in[14];
    float* out = (float*)d_out;

    // workspace layout (floats): Y (16M), XP (16M), hbuf (64K), flags (768 ints)
    float* ws   = (float*)d_ws;
    float* Y    = ws;                        // B*T*H
    float* XP   = ws + (size_t)BB * TT * HH; // B*T*H
    float* hbuf = XP + (size_t)BB * TT * HH; // 2*32*2*512
    int*   flags = (int*)(hbuf + 2 * 32 * 2 * 512); // [3][32][8]

    hipMemsetAsync(flags, 0, 3 * 32 * 8 * sizeof(int), stream);

    const dim3 ggrid(256, 4, 1);
    // layer 0
    gemm_bias_kernel<<<ggrid, 256, 0, stream>>>(x, W_ih[0], b_ih[0], b_hh[0], XP, II);
    scan_kernel<<<256, 512, 0, stream>>>(XP, W_hh[0], Y, hbuf, flags + 0 * 256);
    // layer 1
    gemm_bias_kernel<<<ggrid, 256, 0, stream>>>(Y, W_ih[1], b_ih[1], b_hh[1], XP, HH);
    scan_kernel<<<256, 512, 0, stream>>>(XP, W_hh[1], Y, hbuf, flags + 1 * 256);
    // layer 2
    gemm_bias_kernel<<<ggrid, 256, 0, stream>>>(Y, W_ih[2], b_ih[2], b_hh[2], XP, HH);
    scan_kernel<<<256, 512, 0, stream>>>(XP, W_hh[2], Y, hbuf, flags + 2 * 256);
    // head
    head_kernel<<<BB * CC, 64, 0, stream>>>(Y, W_out, b_out, out);
}